// Round 10
// baseline (867.240 us; speedup 1.0000x reference)
//
#include <hip/hip_runtime.h>

#define M_    512
#define N_    512
#define INF_  1e5f
#define FBIG  1e30f        // off-grid "slowness": updates become >=1e30, fmin keeps INF -> exact INF pad semantics
#define TR    16           // interior tile rows per block
#define TC    32           // interior tile cols per block
#define K_    24           // Jacobi iters per launch (halo); 25 launches x 24 = 600
#define TWR   64           // staged rows (TR+2K)
#define TWC   80           // staged cols (TC+2K)
#define SD    88           // LDS row stride in dwords (16B-aligned rows)
#define QPR   20           // 4-cell quads per row (staged cols 1..80, tail slop-don't-care)
#define NQ    (62*QPR)     // 1240 quads (staged rows 1..62)
#define NT    1024

#if !__has_builtin(__builtin_amdgcn_sqrtf)
#define __builtin_amdgcn_sqrtf sqrtf
#endif

// Godunov upwind cell update (H==1): fast sqrt (<=1ulp), branchless select
__device__ __forceinline__ float cell_upd(float xn0, float xn1, float yn0, float yn1,
                                          float uc, float fh, float t2) {
    float a   = fminf(xn0, xn1);
    float b   = fminf(yn0, yn1);
    float amb = a - b;
    float one = fminf(a, b) + fh;
    float dis = fmaf(-amb, amb, t2);                       // 2*fh^2 - (a-b)^2
    float two = 0.5f * (a + b + __builtin_amdgcn_sqrtf(fmaxf(dis, 0.0f)));
    float un  = (fabsf(amb) >= fh) ? one : two;
    return fminf(uc, un);
}

__device__ __forceinline__ void quad_update(const float* __restrict__ cur,
                                            float* __restrict__ nxt, int off4,
                                            const float* __restrict__ fq,
                                            const float* __restrict__ tq) {
    const int off = off4 * 4;                              // 16B-aligned dword offset
    float4 up = *(const float4*)(cur + off - SD);
    float4 dn = *(const float4*)(cur + off + SD);
    float4 ct = *(const float4*)(cur + off);
    float  lf = cur[off - 1];
    float  rt = cur[off + 4];
    float4 o;
    o.x = cell_upd(up.x, dn.x, lf,   ct.y, ct.x, fq[0], tq[0]);
    o.y = cell_upd(up.y, dn.y, ct.x, ct.z, ct.y, fq[1], tq[1]);
    o.z = cell_upd(up.z, dn.z, ct.y, ct.w, ct.z, fq[2], tq[2]);
    o.w = cell_upd(up.w, dn.w, ct.z, rt,   ct.w, fq[3], tq[3]);
    *(float4*)(nxt + off) = o;
}

// ---------------- temporally-blocked Jacobi, 512 blocks (2 blocks/CU) ----------------
// Tile: 16x32 interior, staged 64x80 halo region. State t is correct on staged
// rows [t,64-t) x cols [t,80-t); iter t updates rows [t+1,62-t] x cols [t+1,78-t].
// Quad (staged row r, start col c) active at iter t <=> t < life = min(r,63-r,c+3,79-c).
// Slop cells outside the shrinking region never feed a needed cell. Off-grid cells
// stay exactly INF (FBIG forces their update >= 1e30; fmin keeps INF).
__global__ __launch_bounds__(NT) void jacobi_k(const float* __restrict__ u_in,
                                               float* __restrict__ u_out,
                                               const float* __restrict__ f,
                                               const int* __restrict__ m1p,
                                               const int* __restrict__ n1p,
                                               int first) {
    __shared__ float sA[TWR * SD];
    __shared__ float sB[TWR * SD];
    const int tid = threadIdx.x;
    const int bx  = blockIdx.x & 15;                       // 16 col-tiles of 32
    const int by  = blockIdx.x >> 4;                       // 32 row-tiles of 16
    const int gr0 = by * TR - K_;
    const int gc0 = bx * TC - K_;
    const int srcR = m1p[0], srcC = n1p[0];

    // stage u tile+halo into sA (lds col = staged col + 3); first launch: fused init
    for (int idx = tid; idx < TWR * TWC; idx += NT) {
        int r = idx / TWC, c = idx - r * TWC;
        int gr = gr0 + r, gc = gc0 + c;
        float uv = INF_;
        if (first) {
            uv = (gr == srcR && gc == srcC) ? 0.0f : INF_;
        } else if ((unsigned)gr < (unsigned)M_ && (unsigned)gc < (unsigned)N_) {
            uv = u_in[(gr << 9) + gc];
        }
        sA[r * SD + c + 3] = uv;
    }

    // fixed per-thread quads: thread tid owns quad tid; tid<NQ-NT also owns quad tid+NT
    int off0, off1 = 0, life0, life1 = 0;
    float fq0[4], tq0[4], fq1[4], tq1[4];
    {
        int qr = tid / QPR, qk = tid - qr * QPR;
        int r0 = qr + 1, c0 = 1 + 4 * qk;
        off0  = 22 * r0 + 1 + qk;                          // offset in float4 units ((r*88+4+4qk)/4)
        life0 = min(min(r0, 63 - r0), min(c0 + 3, 79 - c0));
        #pragma unroll
        for (int j = 0; j < 4; ++j) {
            int gr = gr0 + r0, gc = gc0 + c0 + j;
            float fv = FBIG;
            if ((unsigned)gr < (unsigned)M_ && (unsigned)gc < (unsigned)N_)
                fv = f[(gr << 9) + gc];
            fq0[j] = fv; tq0[j] = 2.0f * fv * fv;
        }
    }
    if (tid + NT < NQ) {
        int qi = tid + NT;
        int qr = qi / QPR, qk = qi - qr * QPR;
        int r1 = qr + 1, c1 = 1 + 4 * qk;
        off1  = 22 * r1 + 1 + qk;
        life1 = min(min(r1, 63 - r1), min(c1 + 3, 79 - c1));
        #pragma unroll
        for (int j = 0; j < 4; ++j) {
            int gr = gr0 + r1, gc = gc0 + c1 + j;
            float fv = FBIG;
            if ((unsigned)gr < (unsigned)M_ && (unsigned)gc < (unsigned)N_)
                fv = f[(gr << 9) + gc];
            fq1[j] = fv; tq1[j] = 2.0f * fv * fv;
        }
    }
    __syncthreads();

    float* cur = sA;
    float* nxt = sB;
    for (int t = 0; t < K_; ++t) {
        if (t < life0) quad_update(cur, nxt, off0, fq0, tq0);
        if (t < life1) quad_update(cur, nxt, off1, fq1, tq1);
        __syncthreads();
        float* tmp = cur; cur = nxt; nxt = tmp;
    }

    // write back valid 16x32 interior: staged rows [24,40) x cols [24,56)
    if (tid < TR * TC) {
        int r = tid >> 5, c = tid & 31;
        u_out[((by * TR + r) << 9) + bx * TC + c] = cur[(K_ + r) * SD + (K_ + 3 + c)];
    }
}

// ---------------- bilinear gather: 3 dword gathers into L2-resident 1MB u ----------------
__device__ __forceinline__ float bil1(const float* __restrict__ u, float gx, float gy) {
    float xu = ceilf(gx),  xl = floorf(gx);
    float yu = ceilf(gy),  yl = floorf(gy);
    int guu = (int)(xu * (float)N_ + yu);
    int gul = (int)(xu * (float)N_ + yl);
    int gll = (int)(xl * (float)N_ + yl);
    float f22 = u[guu];
    float f21 = u[gul];
    float f11 = u[gll];
    float xh = xu - gx, xlw = gx - xl;
    float yh = yu - gy, ylw = gy - yl;
    float w11 = xh * yh, w12 = xh * ylw, w21 = xlw * yh, w22 = xlw * ylw;
    // f_x2y1 used for BOTH w12 and w21 terms, f_x1y2 unused (source quirk); DX*DY == 1
    return w11 * f11 + w12 * f21 + w21 * f21 + w22 * f22;
}

__global__ __launch_bounds__(256) void bilin(const float* __restrict__ u,
                                             const float* __restrict__ gx,
                                             const float* __restrict__ gy,
                                             float* __restrict__ out, int q4) {
    int i = blockIdx.x * blockDim.x + threadIdx.x;
    int stride = gridDim.x * blockDim.x;
    for (; i < q4; i += stride) {
        float4 x = reinterpret_cast<const float4*>(gx)[i];
        float4 y = reinterpret_cast<const float4*>(gy)[i];
        float4 o;
        o.x = bil1(u, x.x, y.x);
        o.y = bil1(u, x.y, y.y);
        o.z = bil1(u, x.z, y.z);
        o.w = bil1(u, x.w, y.w);
        reinterpret_cast<float4*>(out)[i] = o;
    }
}

extern "C" void kernel_launch(void* const* d_in, const int* in_sizes, int n_in,
                              void* d_out, int out_size, void* d_ws, size_t ws_size,
                              hipStream_t stream) {
    const float* f  = (const float*)d_in[0];
    const float* gx = (const float*)d_in[1];
    const float* gy = (const float*)d_in[2];
    const int*   m1 = (const int*)d_in[3];
    const int*   n1 = (const int*)d_in[4];
    float* out = (float*)d_out;

    float* ua = (float*)d_ws;
    float* ub = ua + M_ * N_;
    const int Q = in_sizes[1];

    // 25 launches x 24 sweeps = 600 Jacobi iterations, exactly as the reference.
    // Launch 0 fuses the INF/source init (reads no u_in).
    const float* src = ub;                                 // unused by launch 0
    float*       dst = ua;
    for (int l = 0; l < 25; ++l) {
        jacobi_k<<<512, NT, 0, stream>>>(src, dst, f, m1, n1, l == 0 ? 1 : 0);
        float* t = (float*)src; src = dst; dst = t;
    }
    // after 25 swaps starting dst=ua: final state is in ua (src now points at it)

    bilin<<<4096, 256, 0, stream>>>(src, gx, gy, out, Q / 4);
}

// Round 11
// 856.040 us; speedup vs baseline: 1.0131x; 1.0131x over previous
//
#include <hip/hip_runtime.h>

#define M_    512
#define N_    512
#define INF_  1e5f
#define FBIG  1e30f        // off-grid "slowness": updates become >=1e30, fmin keeps INF -> exact INF pad semantics
#define T_    32           // interior tile per block
#define K_    24           // Jacobi iters per launch (halo); 25 launches x 24 = 600
#define TW    80           // staged tile width
#define SD    88           // LDS row stride in dwords (16B-aligned rows)
#define QPR   20           // 4-cell quads per row
#define NT    1024
#define NW    16           // waves per block

#if !__has_builtin(__builtin_amdgcn_sqrtf)
#define __builtin_amdgcn_sqrtf sqrtf
#endif

// Godunov upwind cell update (H==1): fast sqrt (<=1ulp), branchless select
__device__ __forceinline__ float cell_upd(float xn0, float xn1, float yn0, float yn1,
                                          float uc, float fh, float t2) {
    float a   = fminf(xn0, xn1);
    float b   = fminf(yn0, yn1);
    float amb = a - b;
    float one = fminf(a, b) + fh;
    float dis = fmaf(-amb, amb, t2);                       // 2*fh^2 - (a-b)^2
    float two = 0.5f * (a + b + __builtin_amdgcn_sqrtf(fmaxf(dis, 0.0f)));
    float un  = (fabsf(amb) >= fh) ? one : two;
    return fminf(uc, un);
}

// one Jacobi step for a 1x4 quad; center state held in registers (ct), halo from LDS
__device__ __forceinline__ float4 quad_step(const float* __restrict__ cur, float4 ct, int off4,
                                            const float* __restrict__ fq,
                                            const float* __restrict__ tq) {
    const int off = off4 * 4;                              // 16B-aligned dword offset
    float4 up = *(const float4*)(cur + off - SD);
    float4 dn = *(const float4*)(cur + off + SD);
    float  lf = cur[off - 1];
    float  rt = cur[off + 4];
    float4 o;
    o.x = cell_upd(up.x, dn.x, lf,   ct.y, ct.x, fq[0], tq[0]);
    o.y = cell_upd(up.y, dn.y, ct.x, ct.z, ct.y, fq[1], tq[1]);
    o.z = cell_upd(up.z, dn.z, ct.y, ct.w, ct.z, fq[2], tq[2]);
    o.w = cell_upd(up.w, dn.w, ct.z, rt,   ct.w, fq[3], tq[3]);
    return o;
}

// ---------------- temporally-blocked Jacobi, barrier-free dataflow ----------------
// 256 blocks, 16 waves each. Wave w owns a 5-row band (wave 15: 3 rows) of the
// 78 updatable staged rows. Per-wave LDS flag = iterations completed. Wave w may
// run iter t once flags[w-1]>=t and flags[w+1]>=t (bands are vertically adjacent;
// horizontal deps are intra-wave/lockstep). Double buffer: overwriting state t-1
// at iter t is safe because flags[w±1]>=t implies neighbors finished reading it.
// Trapezoid shrink + slop containment identical to the verified R8 kernel.
__global__ __launch_bounds__(NT) void jacobi_k(const float* __restrict__ u_in,
                                               float* __restrict__ u_out,
                                               const float* __restrict__ f,
                                               const int* __restrict__ m1p,
                                               const int* __restrict__ n1p,
                                               int first) {
    __shared__ float sA[TW * SD];
    __shared__ float sB[TW * SD];
    __shared__ int   flags[NW];
    const int tid  = threadIdx.x;
    const int lane = tid & 63;
    const int w    = tid >> 6;
    const int bx   = blockIdx.x & 15;
    const int by   = blockIdx.x >> 4;
    const int gr0  = by * T_ - K_;
    const int gc0  = bx * T_ - K_;
    const int srcR = m1p[0], srcC = n1p[0];

    if (tid < NW) flags[tid] = 0;

    // stage u tile+halo into sA (lds col = staged col + 3); first launch: fused init
    for (int idx = tid; idx < TW * TW; idx += NT) {
        int r = idx / TW, c = idx - r * TW;
        int gr = gr0 + r, gc = gc0 + c;
        float uv = INF_;
        if (first) {
            uv = (gr == srcR && gc == srcC) ? 0.0f : INF_;
        } else if ((unsigned)gr < (unsigned)M_ && (unsigned)gc < (unsigned)N_) {
            uv = u_in[(gr << 9) + gc];
        }
        sA[r * SD + c + 3] = uv;
    }

    // quad assignment: wave w owns rows rlo..rlo+4 (wave 15: rows 76..78).
    // lane handles quad 'lane' and (if w<15 && lane<36) quad 'lane+64' of its band.
    const int rlo = 1 + 5 * w;
    const int nq  = (w < 15) ? 100 : 60;
    int off0 = 0, life0 = 0, off1 = 0, life1 = 0;
    float fq0[4], tq0[4], fq1[4], tq1[4];
    if (lane < nq) {
        int r = rlo + lane / QPR, qk = lane % QPR, c = 1 + 4 * qk;
        off0  = 22 * r + 1 + qk;                           // offset in float4 units
        life0 = min(min(r, 79 - r), min(c + 3, 79 - c));
        #pragma unroll
        for (int j = 0; j < 4; ++j) {
            int gr = gr0 + r, gc = gc0 + c + j;
            float fv = FBIG;
            if ((unsigned)gr < (unsigned)M_ && (unsigned)gc < (unsigned)N_)
                fv = f[(gr << 9) + gc];
            fq0[j] = fv; tq0[j] = 2.0f * fv * fv;
        }
    }
    if (w < 15 && lane < 36) {
        int q = lane + 64;
        int r = rlo + q / QPR, qk = q % QPR, c = 1 + 4 * qk;
        off1  = 22 * r + 1 + qk;
        life1 = min(min(r, 79 - r), min(c + 3, 79 - c));
        #pragma unroll
        for (int j = 0; j < 4; ++j) {
            int gr = gr0 + r, gc = gc0 + c + j;
            float fv = FBIG;
            if ((unsigned)gr < (unsigned)M_ && (unsigned)gc < (unsigned)N_)
                fv = f[(gr << 9) + gc];
            fq1[j] = fv; tq1[j] = 2.0f * fv * fv;
        }
    }
    __syncthreads();

    // center quads into registers (state 0)
    float4 ct0 = *(const float4*)(sA + off0 * 4);
    float4 ct1 = *(const float4*)(sA + off1 * 4);

    volatile int* vf = flags;
    const float* cur = sA;
    float*       nxt = sB;
    for (int t = 0; t < K_; ++t) {
        if (t) {                                           // t==0: flags all 0, no wait
            if (w > 0)      while (vf[w - 1] < t) __builtin_amdgcn_s_sleep(1);
            if (w < NW - 1) while (vf[w + 1] < t) __builtin_amdgcn_s_sleep(1);
            asm volatile("" ::: "memory");                 // no reads hoisted above the wait
        }
        if (t < life0) { ct0 = quad_step(cur, ct0, off0, fq0, tq0); *(float4*)(nxt + off0 * 4) = ct0; }
        if (t < life1) { ct1 = quad_step(cur, ct1, off1, fq1, tq1); *(float4*)(nxt + off1 * 4) = ct1; }
        asm volatile("s_waitcnt lgkmcnt(0)" ::: "memory"); // writes visible before publish
        if (lane == 0) vf[w] = t + 1;
        const float* tmp = cur; cur = nxt; nxt = (float*)tmp;
    }

    __syncthreads();                                       // all bands at state K_
    // write back valid 32x32 interior: staged [24,56)^2 (state 24 lives in sA: K_ even)
    {
        int r = tid >> 5, c = tid & 31;
        u_out[((by * T_ + r) << 9) + bx * T_ + c] = cur[(K_ + r) * SD + (K_ + 3 + c)];
    }
}

// ---------------- bilinear gather: 3 dword gathers into L2-resident 1MB u ----------------
__device__ __forceinline__ float bil1(const float* __restrict__ u, float gx, float gy) {
    float xu = ceilf(gx),  xl = floorf(gx);
    float yu = ceilf(gy),  yl = floorf(gy);
    int guu = (int)(xu * (float)N_ + yu);
    int gul = (int)(xu * (float)N_ + yl);
    int gll = (int)(xl * (float)N_ + yl);
    float f22 = u[guu];
    float f21 = u[gul];
    float f11 = u[gll];
    float xh = xu - gx, xlw = gx - xl;
    float yh = yu - gy, ylw = gy - yl;
    float w11 = xh * yh, w12 = xh * ylw, w21 = xlw * yh, w22 = xlw * ylw;
    // f_x2y1 used for BOTH w12 and w21 terms, f_x1y2 unused (source quirk); DX*DY == 1
    return w11 * f11 + w12 * f21 + w21 * f21 + w22 * f22;
}

__global__ __launch_bounds__(256) void bilin(const float* __restrict__ u,
                                             const float* __restrict__ gx,
                                             const float* __restrict__ gy,
                                             float* __restrict__ out, int q4) {
    int i = blockIdx.x * blockDim.x + threadIdx.x;
    int stride = gridDim.x * blockDim.x;
    for (; i < q4; i += stride) {
        float4 x = reinterpret_cast<const float4*>(gx)[i];
        float4 y = reinterpret_cast<const float4*>(gy)[i];
        float4 o;
        o.x = bil1(u, x.x, y.x);
        o.y = bil1(u, x.y, y.y);
        o.z = bil1(u, x.z, y.z);
        o.w = bil1(u, x.w, y.w);
        reinterpret_cast<float4*>(out)[i] = o;
    }
}

extern "C" void kernel_launch(void* const* d_in, const int* in_sizes, int n_in,
                              void* d_out, int out_size, void* d_ws, size_t ws_size,
                              hipStream_t stream) {
    const float* f  = (const float*)d_in[0];
    const float* gx = (const float*)d_in[1];
    const float* gy = (const float*)d_in[2];
    const int*   m1 = (const int*)d_in[3];
    const int*   n1 = (const int*)d_in[4];
    float* out = (float*)d_out;

    float* ua = (float*)d_ws;
    float* ub = ua + M_ * N_;
    const int Q = in_sizes[1];

    // 25 launches x 24 sweeps = 600 Jacobi iterations, exactly as the reference.
    // Launch 0 fuses the INF/source init (reads no u_in).
    const float* src = ub;                                 // unused by launch 0
    float*       dst = ua;
    for (int l = 0; l < 25; ++l) {
        jacobi_k<<<256, NT, 0, stream>>>(src, dst, f, m1, n1, l == 0 ? 1 : 0);
        float* t = (float*)src; src = dst; dst = t;
    }

    bilin<<<4096, 256, 0, stream>>>(src, gx, gy, out, Q / 4);
}